// Round 5
// baseline (223.275 us; speedup 1.0000x reference)
//
#include <hip/hip_runtime.h>

typedef unsigned int   u32;
typedef unsigned short u16;
typedef __attribute__((ext_vector_type(8))) short short8;
typedef __attribute__((ext_vector_type(4))) float f32x4;

// B=64 T=256 C=512 H=8 D=64; M = B*T = 16384; K = 512; Nqkv = 1536

__device__ __forceinline__ u16 f2bf(float f) {
    u32 u = __float_as_uint(f);
    u += 0x7fffu + ((u >> 16) & 1u);   // RNE
    return (u16)(u >> 16);
}

// async global->LDS 16B DMA; LDS dest must be wave-uniform base + lane*16.
__device__ __forceinline__ void gload_lds16(const u16* g, u16* l) {
    __builtin_amdgcn_global_load_lds(
        (const __attribute__((address_space(1))) u32*)(const void*)g,
        (__attribute__((address_space(3))) u32*)(void*)l, 16, 0, 0);
}

// ---------------- cast x (fp32 -> bf16) ----------------
__global__ void cast_x_kernel(const float* __restrict__ x, u16* __restrict__ xb) {
    int i = blockIdx.x * 256 + threadIdx.x;
    float4 v = ((const float4*)x)[i];
    ushort4 o;
    o.x = f2bf(v.x); o.y = f2bf(v.y); o.z = f2bf(v.z); o.w = f2bf(v.w);
    ((ushort4*)xb)[i] = o;
}

// -------- pack wq|wk|wv -> bf16 [1536][512] transposed --------
__global__ void pack_wqkv_kernel(const float* __restrict__ wq, const float* __restrict__ wk,
                                 const float* __restrict__ wv, u16* __restrict__ wt) {
    int i = blockIdx.x * 256 + threadIdx.x;
    int n = i >> 9, c = i & 511;
    int proj = n >> 9, hd = n & 511;
    int h = hd >> 6, d = hd & 63;
    const float* w = (proj == 0) ? wq : (proj == 1) ? wk : wv;
    wt[(size_t)n * 512 + c] = f2bf(w[h * 32768 + c * 64 + d]);
}

// -------- pack wo [512][512] -> bf16 transposed [n][k] --------
__global__ void pack_wo_kernel(const float* __restrict__ wo, u16* __restrict__ wt) {
    int i = blockIdx.x * 256 + threadIdx.x;
    int n = i >> 9, k = i & 511;
    wt[(size_t)n * 512 + k] = f2bf(wo[(size_t)k * 512 + n]);
}

// ------------ 256-row fat-tile bf16 MFMA GEMM, K=512, TN, BK=64 ------------
// R15: R14's fat tile was never tested — __launch_bounds__(512) without a
// waves/EU arg let the compiler cap VGPRs at 104 < acc's 128 -> accumulator
// SPILL (WRITE_SIZE 50->83MB = +33MB scratch, MfmaUtil 12%). Fix is the one
// knob: __launch_bounds__(512, 2) = 2 waves/SIMD = 1 block/CU -> 256-VGPR
// budget; kernel needs ~210 (acc 128 + af 32 + bf 16 + addr ~30). LDS already
// forces 1 block/CU (128KB QKV / 96KB outproj), so the bound is free.
// Everything else identical to R14 (epilogues passed, absmax unchanged):
// BM=256, BN=256(QKV)/128(outproj), BK=64, 8 waves, per-wave 128x64.
// Staging map (verified invariant row&7==(lane>>3)&7): call j stages row
// r = j*64 + w*8 + (lane>>3), chunk slot = lane&7, global chunk
// c = slot^(r&7); LDS dest = buf + j*4096 + tid*8 (wave-uniform + lane*16B).
// Fragment reads use the same XOR slots ((h*4+quad)^(lm&7)) -> conflict-free.
template<int NB>
__device__ __forceinline__ void stage_tile(const u16* Ag, const u16* Bg,
                                           u16* Asp, u16* Bsp, int kt) {
    const u16* Agp = Ag + kt * 64;
    const u16* Bgp = Bg + kt * 64;
    #pragma unroll
    for (int j = 0; j < 4; ++j)
        gload_lds16(Agp + j * (64 * 512), Asp + j * 4096);
    #pragma unroll
    for (int j = 0; j < NB; ++j)
        gload_lds16(Bgp + j * (64 * 512), Bsp + j * 4096);
}

template<int EPI, int BN, int NTN>
__global__ __launch_bounds__(512, 2)
void gemm256_kernel(const u16* __restrict__ A, const u16* __restrict__ Bt,
                    float* __restrict__ outf, const float* __restrict__ bo,
                    u16* __restrict__ Qb, u16* __restrict__ Kb, u16* __restrict__ Vb,
                    const float* __restrict__ bq, const float* __restrict__ bk,
                    const float* __restrict__ bv) {
    __shared__ __align__(16) u16 As[2][256 * 64];   // 64KB
    __shared__ __align__(16) u16 Bs[2][BN * 64];    // 64KB or 32KB
    constexpr int NBCALL = BN / 64;   // B stage calls per thread (4 or 2)
    constexpr int FN = BN / 64;       // n-fragments per wave (4 or 2)

    const int tid = threadIdx.x;
    const int bid = blockIdx.x;
    const int xcd = bid & 7;
    const int idx = bid >> 3;
    const int m0 = (xcd * 8 + idx / NTN) * 256;   // 64 m-tiles, 8 per XCD
    const int nt = idx % NTN;
    const int n0 = nt * BN;
    const int w = tid >> 6, lane = tid & 63;
    const int srow = w * 8 + (lane >> 3);               // + j*64 per call
    const int sc   = (lane & 7) ^ ((lane >> 3) & 7);    // global 16B-chunk
    const u16* Ag = A  + (size_t)(m0 + srow) * 512 + sc * 8;
    const u16* Bg = Bt + (size_t)(n0 + srow) * 512 + sc * 8;

    const int wrow = (w >> 2) * 128;          // 2 wave-rows of 128
    const int wcol = (w & 3) * (BN / 4);      // 4 wave-cols
    const int lm = lane & 15, quad = lane >> 4;
    const int l7 = lm & 7;

    f32x4 acc[8][FN] = {};

    // prologue: stage tile 0 into buffer 0
    stage_tile<NBCALL>(Ag, Bg, As[0] + tid * 8, Bs[0] + tid * 8, 0);

    #pragma unroll 1
    for (int kt = 0; kt < 8; ++kt) {
        __syncthreads();   // tile kt DMA drained; other buffer's old reads done
        if (kt < 7)
            stage_tile<NBCALL>(Ag, Bg, As[(kt + 1) & 1] + tid * 8,
                               Bs[(kt + 1) & 1] + tid * 8, kt + 1);
        const u16* Ac = As[kt & 1];
        const u16* Bc = Bs[kt & 1];
        #pragma unroll
        for (int h = 0; h < 2; ++h) {
            const int slot = ((h * 4 + quad) ^ l7) * 8;
            short8 af[8], bf[FN];
            #pragma unroll
            for (int mi = 0; mi < 8; ++mi)
                af[mi] = *(const short8*)(Ac + (wrow + mi * 16 + lm) * 64 + slot);
            #pragma unroll
            for (int ni = 0; ni < FN; ++ni)
                bf[ni] = *(const short8*)(Bc + (wcol + ni * 16 + lm) * 64 + slot);
            #pragma unroll
            for (int mi = 0; mi < 8; ++mi)
                #pragma unroll
                for (int ni = 0; ni < FN; ++ni)
                    acc[mi][ni] = __builtin_amdgcn_mfma_f32_16x16x32_bf16(af[mi], bf[ni], acc[mi][ni], 0, 0, 0);
        }
    }

    if (EPI == 1) {
        #pragma unroll
        for (int ni = 0; ni < FN; ++ni) {
            int ncol = n0 + wcol + ni * 16 + lm;
            float bias = bo[ncol];
            #pragma unroll
            for (int mi = 0; mi < 8; ++mi) {
                int mbase = m0 + wrow + mi * 16 + quad * 4;
                #pragma unroll
                for (int r = 0; r < 4; ++r)
                    outf[(size_t)(mbase + r) * 512 + ncol] = acc[mi][ni][r] + bias;
            }
        }
    } else {
        // QKV epilogue: BN=256, NTN=6. proj = nt>>1 (block-uniform);
        // head hh = (nt&1)*4 + (w&3) (wave-uniform); d = ni*16 + lm.
        const int proj = nt >> 1;
        const int hh = (nt & 1) * 4 + (w & 3);
        const float* bptr = (proj == 0) ? bq : (proj == 1) ? bk : bv;
        u16* dst = (proj == 0) ? Qb : (proj == 1) ? Kb : Vb;
        #pragma unroll
        for (int ni = 0; ni < FN; ++ni) {
            int d = ni * 16 + lm;
            float bias = bptr[hh * 64 + d];
            #pragma unroll
            for (int mi = 0; mi < 8; ++mi) {
                int mbase = m0 + wrow + mi * 16 + quad * 4;
                #pragma unroll
                for (int r = 0; r < 4; ++r) {
                    int mrow = mbase + r;
                    int b = mrow >> 8, t = mrow & 255;
                    size_t idxo = (proj == 2)
                        ? ((size_t)((b * 8 + hh) * 64 + d) * 256 + t)    // Vt [head][d][t]
                        : ((size_t)((b * 8 + hh) * 256 + t) * 64 + d);  // Q/K [head][t][d]
                    dst[idxo] = f2bf(acc[mi][ni][r] + bias);
                }
            }
        }
    }
}

// ---------------- MFMA flash attention (unchanged) ----------
// TWO wgs per (b,h) (iset 0: i in {0,3}; iset 1: i in {1,2}), XCD-co-located.
// K staged in LDS (XOR 16B-chunk swizzle, conflict-free); V fragments read
// directly from global Vt[head][d][t], hoisted above softmax. LDS 40KB/wg.
__global__ __launch_bounds__(256)
void attn_mfma_kernel(const u16* __restrict__ Qg, const u16* __restrict__ Kg,
                      const u16* __restrict__ Vtg, u16* __restrict__ attn) {
    __shared__ __align__(16) u16 lds[20480];   // K:0..16383 | P: 16384 + w*1024
    const int bid = blockIdx.x;
    const int head = (bid & 7) * 64 + ((bid >> 3) >> 1);
    const int iset = (bid >> 3) & 1;
    const int b = head >> 3, h = head & 7;
    const int tid = threadIdx.x;
    const size_t hb = (size_t)head * 16384;

    {
        const uint4* Ksrc = (const uint4*)(Kg + hb);
        uint4* L4 = (uint4*)lds;
        #pragma unroll
        for (int it = 0; it < 8; ++it) {
            int g = it * 256 + tid;
            int kr = g >> 3, kc = g & 7;
            L4[kr * 8 + (kc ^ (kr & 7))] = Ksrc[g];
        }
    }
    __syncthreads();

    const int w = tid >> 6, lane = tid & 63;
    const int lm = lane & 15, quad = lane >> 4;
    const int l7 = lm & 7;

    const int kx0 = (quad ^ l7) * 8;
    const int kx1 = ((4 + quad) ^ l7) * 8;
    const u16* Kbase = lds + lm * 64;
    const u16* Vg = Vtg + hb;
    const int Pbase = 16384 + w * 1024;
    const int x0 = (lm >> 3) & 1;
    const int pw_even = Pbase + quad * 16 + l7 + x0 * 8;
    const int pw_odd  = Pbase + quad * 16 + l7 + (x0 ^ 1) * 8;
    const int pr0 = Pbase + ((lm & 3) * 4 + (quad >> 1)) * 64
                  + (2 * (lm >> 2) + ((quad & 1) ^ (lm & 1))) * 8;

    #pragma unroll 1
    for (int ii = 0; ii < 2; ++ii) {
        const int i = iset ? (ii ? 2 : 1) : (ii ? 3 : 0);
        const int t0 = i * 64 + w * 16;
        short8 qa0 = *(const short8*)(Qg + hb + (size_t)(t0 + lm) * 64 + quad * 8);
        short8 qa1 = *(const short8*)(Qg + hb + (size_t)(t0 + lm) * 64 + 32 + quad * 8);
        f32x4 O[4] = {};
        float mr[4] = {-INFINITY, -INFINITY, -INFINITY, -INFINITY};
        float lr[4] = {0.f, 0.f, 0.f, 0.f};

        #pragma unroll 1
        for (int j = 0; j <= i; ++j) {
            f32x4 S[4] = {};
            #pragma unroll
            for (int ni = 0; ni < 4; ++ni) {
                const u16* kp = Kbase + j * 4096 + ni * 1024;
                short8 kb0 = *(const short8*)(kp + kx0);
                short8 kb1 = *(const short8*)(kp + kx1);
                S[ni] = __builtin_amdgcn_mfma_f32_16x16x32_bf16(qa0, kb0, S[ni], 0, 0, 0);
                S[ni] = __builtin_amdgcn_mfma_f32_16x16x32_bf16(qa1, kb1, S[ni], 0, 0, 0);
            }
            // hoisted V-fragment loads (P-independent; overlap softmax+barrier)
            short8 vb[4][2];
            #pragma unroll
            for (int nd = 0; nd < 4; ++nd) {
                const u16* vp = Vg + (size_t)(nd * 16 + lm) * 256 + j * 64;
                vb[nd][0] = *(const short8*)(vp + quad * 8);
                vb[nd][1] = *(const short8*)(vp + 32 + quad * 8);
            }
            if (j == i) {
                #pragma unroll
                for (int ni = 0; ni < 4; ++ni) {
                    int scol = ni * 16 + lm;
                    #pragma unroll
                    for (int rr = 0; rr < 4; ++rr) {
                        int tloc = w * 16 + quad * 4 + rr;
                        S[ni][rr] = (scol > tloc) ? -INFINITY : S[ni][rr] * 0.125f;
                    }
                }
            } else {
                #pragma unroll
                for (int ni = 0; ni < 4; ++ni)
                    #pragma unroll
                    for (int rr = 0; rr < 4; ++rr)
                        S[ni][rr] *= 0.125f;
            }
            float alpha[4];
            #pragma unroll
            for (int rr = 0; rr < 4; ++rr) {
                float mx = fmaxf(fmaxf(S[0][rr], S[1][rr]), fmaxf(S[2][rr], S[3][rr]));
                mx = fmaxf(mx, __shfl_xor(mx, 1));
                mx = fmaxf(mx, __shfl_xor(mx, 2));
                mx = fmaxf(mx, __shfl_xor(mx, 4));
                mx = fmaxf(mx, __shfl_xor(mx, 8));
                float mnew = fmaxf(mr[rr], mx);
                alpha[rr] = __expf(mr[rr] - mnew);
                mr[rr] = mnew;
            }
            float rs[4] = {0.f, 0.f, 0.f, 0.f};
            #pragma unroll
            for (int ni = 0; ni < 4; ++ni) {
                #pragma unroll
                for (int rr = 0; rr < 4; ++rr) {
                    float p = __expf(S[ni][rr] - mr[rr]);
                    rs[rr] += p;
                    int addr = ((rr & 1) ? pw_odd : pw_even) + (rr * 4 + ni) * 64;
                    lds[addr] = f2bf(p);
                }
            }
            #pragma unroll
            for (int rr = 0; rr < 4; ++rr) {
                float s = rs[rr];
                s += __shfl_xor(s, 1);
                s += __shfl_xor(s, 2);
                s += __shfl_xor(s, 4);
                s += __shfl_xor(s, 8);
                lr[rr] = lr[rr] * alpha[rr] + s;
                O[0][rr] *= alpha[rr]; O[1][rr] *= alpha[rr];
                O[2][rr] *= alpha[rr]; O[3][rr] *= alpha[rr];
            }
            __syncthreads();   // P write -> read ordering
            short8 pa0 = *(const short8*)(lds + pr0);
            short8 pa1 = *(const short8*)(lds + pr0 + 128);
            #pragma unroll
            for (int nd = 0; nd < 4; ++nd) {
                O[nd] = __builtin_amdgcn_mfma_f32_16x16x32_bf16(pa0, vb[nd][0], O[nd], 0, 0, 0);
                O[nd] = __builtin_amdgcn_mfma_f32_16x16x32_bf16(pa1, vb[nd][1], O[nd], 0, 0, 0);
            }
        }
        #pragma unroll
        for (int rr = 0; rr < 4; ++rr) {
            float inv = 1.0f / lr[rr];
            int t = t0 + quad * 4 + rr;
            u16* op = attn + (size_t)(b * 256 + t) * 512 + h * 64 + lm;
            op[0]  = f2bf(O[0][rr] * inv);
            op[16] = f2bf(O[1][rr] * inv);
            op[32] = f2bf(O[2][rr] * inv);
            op[48] = f2bf(O[3][rr] * inv);
        }
    }
}

extern "C" void kernel_launch(void* const* d_in, const int* in_sizes, int n_in,
                              void* d_out, int out_size, void* d_ws, size_t ws_size,
                              hipStream_t stream) {
    const float* x  = (const float*)d_in[0];
    const float* wq = (const float*)d_in[1];
    const float* wk = (const float*)d_in[2];
    const float* wv = (const float*)d_in[3];
    const float* bq = (const float*)d_in[4];
    const float* bk = (const float*)d_in[5];
    const float* bv = (const float*)d_in[6];
    const float* wo = (const float*)d_in[7];
    const float* bo = (const float*)d_in[8];
    float* out = (float*)d_out;

    char* ws = (char*)d_ws;
    const size_t SZ = 16777216;                  // 16384*512*2 bytes
    u16* xb    = (u16*)(ws);
    u16* Qb    = (u16*)(ws + SZ);
    u16* Kb    = (u16*)(ws + 2 * SZ);
    u16* Vt    = (u16*)(ws + 3 * SZ);            // [head][d][t]
    u16* attn  = (u16*)(ws + 4 * SZ);
    u16* wqkvT = (u16*)(ws + 5 * SZ);
    u16* woT   = (u16*)(ws + 5 * SZ + 1572864);

    cast_x_kernel<<<8192, 256, 0, stream>>>(x, xb);
    pack_wqkv_kernel<<<3072, 256, 0, stream>>>(wq, wk, wv, wqkvT);
    pack_wo_kernel<<<1024, 256, 0, stream>>>(wo, woT);

    // QKV: M=16384 (64 m-tiles of 256), N=1536 (6 n-tiles of 256) -> 384 blocks
    gemm256_kernel<0, 256, 6><<<384, 512, 0, stream>>>(
        xb, wqkvT, nullptr, nullptr, Qb, Kb, Vt, bq, bk, bv);

    attn_mfma_kernel<<<1024, 256, 0, stream>>>(Qb, Kb, Vt, attn);

    // out-proj: M=16384 (64 m-tiles), N=512 (4 n-tiles of 128) -> 256 blocks
    gemm256_kernel<1, 128, 4><<<256, 512, 0, stream>>>(
        attn, woT, out, bo, nullptr, nullptr, nullptr, nullptr, nullptr, nullptr);
}

// Round 6
// 222.613 us; speedup vs baseline: 1.0030x; 1.0030x over previous
//
#include <hip/hip_runtime.h>

typedef unsigned int   u32;
typedef unsigned short u16;
typedef __attribute__((ext_vector_type(8))) short short8;
typedef __attribute__((ext_vector_type(4))) float f32x4;

// B=64 T=256 C=512 H=8 D=64; M = B*T = 16384; K = 512; Nqkv = 1536

__device__ __forceinline__ u16 f2bf(float f) {
    u32 u = __float_as_uint(f);
    u += 0x7fffu + ((u >> 16) & 1u);   // RNE
    return (u16)(u >> 16);
}

// async global->LDS 16B DMA; LDS dest must be wave-uniform base + lane*16.
__device__ __forceinline__ void gload_lds16(const u16* g, u16* l) {
    __builtin_amdgcn_global_load_lds(
        (const __attribute__((address_space(1))) u32*)(const void*)g,
        (__attribute__((address_space(3))) u32*)(void*)l, 16, 0, 0);
}

// ---------------- cast x (fp32 -> bf16) ----------------
__global__ void cast_x_kernel(const float* __restrict__ x, u16* __restrict__ xb) {
    int i = blockIdx.x * 256 + threadIdx.x;
    float4 v = ((const float4*)x)[i];
    ushort4 o;
    o.x = f2bf(v.x); o.y = f2bf(v.y); o.z = f2bf(v.z); o.w = f2bf(v.w);
    ((ushort4*)xb)[i] = o;
}

// -------- pack wq|wk|wv -> bf16 [1536][512] transposed --------
__global__ void pack_wqkv_kernel(const float* __restrict__ wq, const float* __restrict__ wk,
                                 const float* __restrict__ wv, u16* __restrict__ wt) {
    int i = blockIdx.x * 256 + threadIdx.x;
    int n = i >> 9, c = i & 511;
    int proj = n >> 9, hd = n & 511;
    int h = hd >> 6, d = hd & 63;
    const float* w = (proj == 0) ? wq : (proj == 1) ? wk : wv;
    wt[(size_t)n * 512 + c] = f2bf(w[h * 32768 + c * 64 + d]);
}

// -------- pack wo [512][512] -> bf16 transposed [n][k] --------
__global__ void pack_wo_kernel(const float* __restrict__ wo, u16* __restrict__ wt) {
    int i = blockIdx.x * 256 + threadIdx.x;
    int n = i >> 9, k = i & 511;
    wt[(size_t)n * 512 + k] = f2bf(wo[(size_t)k * 512 + n]);
}

// ---------- 128x128 bf16 MFMA GEMM, A-only LDS dbuf, B direct from L2 -------
// R16: R10-R15 fit — per-BLOCK DMA service ~8-10 B/cy is invariant (m102:
// ~2000cy/iter at 1 blk/CU); aggregate scales with INDEPENDENT resident
// barrier domains (m97: ~22 B/cy at 3-4 blocks). We were LDS-capped at 2
// (64KB A+B dbuf). Fix: stop staging B (1.5MB wqkvT / 0.5MB woT, L2-hot,
// shared across all m-blocks on the XCD) — read B fragments per-lane from
// global. LDS 32KB/block -> 4 blocks/CU (launch_bounds(256,4): 128-VGPR cap;
// demand ~116 = acc 64 + af 16 + bf 16 + addr). DMA bytes halve AND drain
// concurrency doubles. Geometry/staging/epilogue byte-identical to the R0
// kernel (passed, 88 VGPR): 4 waves, per-wave 64x64, acc[4][4].
// Staging map (verified): call j stages row r=j*32+w*8+(l>>3), LDS slot=l&7,
// global chunk c=(l&7)^((l>>3)&7)=slot^(r&7). Fragment read slot
// ((h*4+quad)^(lm&7)) -> stored chunk = slot^(row&7) = h*4+quad, so the
// B-global equivalent k-offset is simply kt*64 + h*32 + quad*8 (no XOR).
// Bonus: V epilogue writes are t-consecutive per lane -> ushort4 stores.
template<int EPI, int NT>
__global__ __launch_bounds__(256, 4)
void gemm128_kernel(const u16* __restrict__ A, const u16* __restrict__ Bt,
                    float* __restrict__ outf, const float* __restrict__ bo,
                    u16* __restrict__ Qb, u16* __restrict__ Kb, u16* __restrict__ Vb,
                    const float* __restrict__ bq, const float* __restrict__ bk,
                    const float* __restrict__ bv) {
    __shared__ __align__(16) u16 As[2][8192];   // 128 rows x 64 k, 16KB per buffer
    const int tid = threadIdx.x;
    const int bid = blockIdx.x;
    const int xcd = bid & 7;
    const int k8  = bid >> 3;                 // 0 .. 16*NT-1
    const int m0 = (xcd * 16 + k8 / NT) * 128;
    const int n0 = (k8 % NT) * 128;
    const int w = tid >> 6, lane = tid & 63;
    const int srow = w * 8 + (lane >> 3);               // + j*32
    const int sc   = (lane & 7) ^ ((lane >> 3) & 7);    // global 16B-chunk
    const u16* Ag = A + (size_t)(m0 + srow) * 512 + sc * 8;
    const int lofs = w * 512 + lane * 8;                // + j*2048 (u16 units)

    const int wrow = (w >> 1) * 64, wcol = (w & 1) * 64;
    const int lm = lane & 15, quad = lane >> 4;
    const int l7 = lm & 7;

    // B fragment base: row = n0 + wcol + ni*16 + lm, k-off = kt*64+h*32+quad*8
    const u16* Bg0 = Bt + (size_t)(n0 + wcol + lm) * 512 + quad * 8;

    f32x4 acc[4][4] = {};

#define STAGE_A(kt, b) do {                                      \
        const u16* Agp = Ag + (kt) * 64;                         \
        u16* Asp = As[(b)] + lofs;                               \
        gload_lds16(Agp,             Asp);                       \
        gload_lds16(Agp + 32 * 512,  Asp + 2048);                \
        gload_lds16(Agp + 64 * 512,  Asp + 4096);                \
        gload_lds16(Agp + 96 * 512,  Asp + 6144);                \
    } while (0)

    // prologue: stage tile 0 into buffer 0
    STAGE_A(0, 0);

    #pragma unroll 1
    for (int kt = 0; kt < 8; ++kt) {
        __syncthreads();   // tile kt DMA drained; other buffer's old reads done
        if (kt < 7) STAGE_A(kt + 1, (kt + 1) & 1);
        const u16* Ac = As[kt & 1];
        #pragma unroll
        for (int h = 0; h < 2; ++h) {
            const int slot = ((h * 4 + quad) ^ l7) * 8;
            short8 af[4], bf[4];
            #pragma unroll
            for (int mi = 0; mi < 4; ++mi)
                af[mi] = *(const short8*)(Ac + (wrow + mi * 16 + lm) * 64 + slot);
            #pragma unroll
            for (int ni = 0; ni < 4; ++ni)
                bf[ni] = *(const short8*)(Bg0 + (size_t)(ni * 16) * 512 + kt * 64 + h * 32);
            #pragma unroll
            for (int mi = 0; mi < 4; ++mi)
                #pragma unroll
                for (int ni = 0; ni < 4; ++ni)
                    acc[mi][ni] = __builtin_amdgcn_mfma_f32_16x16x32_bf16(af[mi], bf[ni], acc[mi][ni], 0, 0, 0);
        }
    }
#undef STAGE_A

    if (EPI == 1) {
        #pragma unroll
        for (int ni = 0; ni < 4; ++ni) {
            int ncol = n0 + wcol + ni * 16 + lm;
            float bias = bo[ncol];
            #pragma unroll
            for (int mi = 0; mi < 4; ++mi) {
                int mbase = m0 + wrow + mi * 16 + quad * 4;
                #pragma unroll
                for (int r = 0; r < 4; ++r)
                    outf[(size_t)(mbase + r) * 512 + ncol] = acc[mi][ni][r] + bias;
            }
        }
    } else {
        #pragma unroll
        for (int ni = 0; ni < 4; ++ni) {
            int ncol = n0 + wcol + ni * 16 + lm;
            int proj = ncol >> 9, hd = ncol & 511;
            int h = hd >> 6, d = hd & 63;
            const float* bptr = (proj == 0) ? bq : (proj == 1) ? bk : bv;
            u16* dst = (proj == 0) ? Qb : (proj == 1) ? Kb : Vb;
            float bias = bptr[hd];
            #pragma unroll
            for (int mi = 0; mi < 4; ++mi) {
                int mbase = m0 + wrow + mi * 16 + quad * 4;
                if (proj == 2) {
                    // Vt [head][d][t]: r -> t consecutive, same b (mbase%4==0,
                    // mbase&255 <= 252). One ushort4 store.
                    int b = mbase >> 8, t = mbase & 255;
                    ushort4 v4;
                    v4.x = f2bf(acc[mi][ni][0] + bias);
                    v4.y = f2bf(acc[mi][ni][1] + bias);
                    v4.z = f2bf(acc[mi][ni][2] + bias);
                    v4.w = f2bf(acc[mi][ni][3] + bias);
                    *(ushort4*)(dst + ((size_t)((b * 8 + h) * 64 + d) * 256 + t)) = v4;
                } else {
                    #pragma unroll
                    for (int r = 0; r < 4; ++r) {
                        int mrow = mbase + r;
                        int b = mrow >> 8, t = mrow & 255;
                        dst[(size_t)((b * 8 + h) * 256 + t) * 64 + d] =
                            f2bf(acc[mi][ni][r] + bias);
                    }
                }
            }
        }
    }
}

// ---------------- MFMA flash attention (unchanged) ----------
// TWO wgs per (b,h) (iset 0: i in {0,3}; iset 1: i in {1,2}), XCD-co-located.
// K staged in LDS (XOR 16B-chunk swizzle, conflict-free); V fragments read
// directly from global Vt[head][d][t], hoisted above softmax. LDS 40KB/wg.
__global__ __launch_bounds__(256)
void attn_mfma_kernel(const u16* __restrict__ Qg, const u16* __restrict__ Kg,
                      const u16* __restrict__ Vtg, u16* __restrict__ attn) {
    __shared__ __align__(16) u16 lds[20480];   // K:0..16383 | P: 16384 + w*1024
    const int bid = blockIdx.x;
    const int head = (bid & 7) * 64 + ((bid >> 3) >> 1);
    const int iset = (bid >> 3) & 1;
    const int b = head >> 3, h = head & 7;
    const int tid = threadIdx.x;
    const size_t hb = (size_t)head * 16384;

    {
        const uint4* Ksrc = (const uint4*)(Kg + hb);
        uint4* L4 = (uint4*)lds;
        #pragma unroll
        for (int it = 0; it < 8; ++it) {
            int g = it * 256 + tid;
            int kr = g >> 3, kc = g & 7;
            L4[kr * 8 + (kc ^ (kr & 7))] = Ksrc[g];
        }
    }
    __syncthreads();

    const int w = tid >> 6, lane = tid & 63;
    const int lm = lane & 15, quad = lane >> 4;
    const int l7 = lm & 7;

    const int kx0 = (quad ^ l7) * 8;
    const int kx1 = ((4 + quad) ^ l7) * 8;
    const u16* Kbase = lds + lm * 64;
    const u16* Vg = Vtg + hb;
    const int Pbase = 16384 + w * 1024;
    const int x0 = (lm >> 3) & 1;
    const int pw_even = Pbase + quad * 16 + l7 + x0 * 8;
    const int pw_odd  = Pbase + quad * 16 + l7 + (x0 ^ 1) * 8;
    const int pr0 = Pbase + ((lm & 3) * 4 + (quad >> 1)) * 64
                  + (2 * (lm >> 2) + ((quad & 1) ^ (lm & 1))) * 8;

    #pragma unroll 1
    for (int ii = 0; ii < 2; ++ii) {
        const int i = iset ? (ii ? 2 : 1) : (ii ? 3 : 0);
        const int t0 = i * 64 + w * 16;
        short8 qa0 = *(const short8*)(Qg + hb + (size_t)(t0 + lm) * 64 + quad * 8);
        short8 qa1 = *(const short8*)(Qg + hb + (size_t)(t0 + lm) * 64 + 32 + quad * 8);
        f32x4 O[4] = {};
        float mr[4] = {-INFINITY, -INFINITY, -INFINITY, -INFINITY};
        float lr[4] = {0.f, 0.f, 0.f, 0.f};

        #pragma unroll 1
        for (int j = 0; j <= i; ++j) {
            f32x4 S[4] = {};
            #pragma unroll
            for (int ni = 0; ni < 4; ++ni) {
                const u16* kp = Kbase + j * 4096 + ni * 1024;
                short8 kb0 = *(const short8*)(kp + kx0);
                short8 kb1 = *(const short8*)(kp + kx1);
                S[ni] = __builtin_amdgcn_mfma_f32_16x16x32_bf16(qa0, kb0, S[ni], 0, 0, 0);
                S[ni] = __builtin_amdgcn_mfma_f32_16x16x32_bf16(qa1, kb1, S[ni], 0, 0, 0);
            }
            // hoisted V-fragment loads (P-independent; overlap softmax+barrier)
            short8 vb[4][2];
            #pragma unroll
            for (int nd = 0; nd < 4; ++nd) {
                const u16* vp = Vg + (size_t)(nd * 16 + lm) * 256 + j * 64;
                vb[nd][0] = *(const short8*)(vp + quad * 8);
                vb[nd][1] = *(const short8*)(vp + 32 + quad * 8);
            }
            if (j == i) {
                #pragma unroll
                for (int ni = 0; ni < 4; ++ni) {
                    int scol = ni * 16 + lm;
                    #pragma unroll
                    for (int rr = 0; rr < 4; ++rr) {
                        int tloc = w * 16 + quad * 4 + rr;
                        S[ni][rr] = (scol > tloc) ? -INFINITY : S[ni][rr] * 0.125f;
                    }
                }
            } else {
                #pragma unroll
                for (int ni = 0; ni < 4; ++ni)
                    #pragma unroll
                    for (int rr = 0; rr < 4; ++rr)
                        S[ni][rr] *= 0.125f;
            }
            float alpha[4];
            #pragma unroll
            for (int rr = 0; rr < 4; ++rr) {
                float mx = fmaxf(fmaxf(S[0][rr], S[1][rr]), fmaxf(S[2][rr], S[3][rr]));
                mx = fmaxf(mx, __shfl_xor(mx, 1));
                mx = fmaxf(mx, __shfl_xor(mx, 2));
                mx = fmaxf(mx, __shfl_xor(mx, 4));
                mx = fmaxf(mx, __shfl_xor(mx, 8));
                float mnew = fmaxf(mr[rr], mx);
                alpha[rr] = __expf(mr[rr] - mnew);
                mr[rr] = mnew;
            }
            float rs[4] = {0.f, 0.f, 0.f, 0.f};
            #pragma unroll
            for (int ni = 0; ni < 4; ++ni) {
                #pragma unroll
                for (int rr = 0; rr < 4; ++rr) {
                    float p = __expf(S[ni][rr] - mr[rr]);
                    rs[rr] += p;
                    int addr = ((rr & 1) ? pw_odd : pw_even) + (rr * 4 + ni) * 64;
                    lds[addr] = f2bf(p);
                }
            }
            #pragma unroll
            for (int rr = 0; rr < 4; ++rr) {
                float s = rs[rr];
                s += __shfl_xor(s, 1);
                s += __shfl_xor(s, 2);
                s += __shfl_xor(s, 4);
                s += __shfl_xor(s, 8);
                lr[rr] = lr[rr] * alpha[rr] + s;
                O[0][rr] *= alpha[rr]; O[1][rr] *= alpha[rr];
                O[2][rr] *= alpha[rr]; O[3][rr] *= alpha[rr];
            }
            __syncthreads();   // P write -> read ordering
            short8 pa0 = *(const short8*)(lds + pr0);
            short8 pa1 = *(const short8*)(lds + pr0 + 128);
            #pragma unroll
            for (int nd = 0; nd < 4; ++nd) {
                O[nd] = __builtin_amdgcn_mfma_f32_16x16x32_bf16(pa0, vb[nd][0], O[nd], 0, 0, 0);
                O[nd] = __builtin_amdgcn_mfma_f32_16x16x32_bf16(pa1, vb[nd][1], O[nd], 0, 0, 0);
            }
        }
        #pragma unroll
        for (int rr = 0; rr < 4; ++rr) {
            float inv = 1.0f / lr[rr];
            int t = t0 + quad * 4 + rr;
            u16* op = attn + (size_t)(b * 256 + t) * 512 + h * 64 + lm;
            op[0]  = f2bf(O[0][rr] * inv);
            op[16] = f2bf(O[1][rr] * inv);
            op[32] = f2bf(O[2][rr] * inv);
            op[48] = f2bf(O[3][rr] * inv);
        }
    }
}

extern "C" void kernel_launch(void* const* d_in, const int* in_sizes, int n_in,
                              void* d_out, int out_size, void* d_ws, size_t ws_size,
                              hipStream_t stream) {
    const float* x  = (const float*)d_in[0];
    const float* wq = (const float*)d_in[1];
    const float* wk = (const float*)d_in[2];
    const float* wv = (const float*)d_in[3];
    const float* bq = (const float*)d_in[4];
    const float* bk = (const float*)d_in[5];
    const float* bv = (const float*)d_in[6];
    const float* wo = (const float*)d_in[7];
    const float* bo = (const float*)d_in[8];
    float* out = (float*)d_out;

    char* ws = (char*)d_ws;
    const size_t SZ = 16777216;                  // 16384*512*2 bytes
    u16* xb    = (u16*)(ws);
    u16* Qb    = (u16*)(ws + SZ);
    u16* Kb    = (u16*)(ws + 2 * SZ);
    u16* Vt    = (u16*)(ws + 3 * SZ);            // [head][d][t]
    u16* attn  = (u16*)(ws + 4 * SZ);
    u16* wqkvT = (u16*)(ws + 5 * SZ);
    u16* woT   = (u16*)(ws + 5 * SZ + 1572864);

    cast_x_kernel<<<8192, 256, 0, stream>>>(x, xb);
    pack_wqkv_kernel<<<3072, 256, 0, stream>>>(wq, wk, wv, wqkvT);
    pack_wo_kernel<<<1024, 256, 0, stream>>>(wo, woT);

    gemm128_kernel<0, 12><<<1536, 256, 0, stream>>>(
        xb, wqkvT, nullptr, nullptr, Qb, Kb, Vt, bq, bk, bv);

    attn_mfma_kernel<<<1024, 256, 0, stream>>>(Qb, Kb, Vt, attn);

    gemm128_kernel<1, 4><<<512, 256, 0, stream>>>(
        attn, woT, out, bo, nullptr, nullptr, nullptr, nullptr, nullptr, nullptr);
}

// Round 7
// 220.324 us; speedup vs baseline: 1.0134x; 1.0104x over previous
//
#include <hip/hip_runtime.h>

typedef unsigned int   u32;
typedef unsigned short u16;
typedef __attribute__((ext_vector_type(8))) short short8;
typedef __attribute__((ext_vector_type(4))) float f32x4;

// B=64 T=256 C=512 H=8 D=64; M = B*T = 16384; K = 512; Nqkv = 1536

__device__ __forceinline__ u16 f2bf(float f) {
    u32 u = __float_as_uint(f);
    u += 0x7fffu + ((u >> 16) & 1u);   // RNE
    return (u16)(u >> 16);
}

// async global->LDS 16B DMA; LDS dest must be wave-uniform base + lane*16.
__device__ __forceinline__ void gload_lds16(const u16* g, u16* l) {
    __builtin_amdgcn_global_load_lds(
        (const __attribute__((address_space(1))) u32*)(const void*)g,
        (__attribute__((address_space(3))) u32*)(void*)l, 16, 0, 0);
}

// ---------------- cast x (fp32 -> bf16) ----------------
__global__ void cast_x_kernel(const float* __restrict__ x, u16* __restrict__ xb) {
    int i = blockIdx.x * 256 + threadIdx.x;
    float4 v = ((const float4*)x)[i];
    ushort4 o;
    o.x = f2bf(v.x); o.y = f2bf(v.y); o.z = f2bf(v.z); o.w = f2bf(v.w);
    ((ushort4*)xb)[i] = o;
}

// -------- pack wq|wk|wv -> bf16 [1536][512] transposed --------
__global__ void pack_wqkv_kernel(const float* __restrict__ wq, const float* __restrict__ wk,
                                 const float* __restrict__ wv, u16* __restrict__ wt) {
    int i = blockIdx.x * 256 + threadIdx.x;
    int n = i >> 9, c = i & 511;
    int proj = n >> 9, hd = n & 511;
    int h = hd >> 6, d = hd & 63;
    const float* w = (proj == 0) ? wq : (proj == 1) ? wk : wv;
    wt[(size_t)n * 512 + c] = f2bf(w[h * 32768 + c * 64 + d]);
}

// -------- pack wo [512][512] -> bf16 transposed [n][k] --------
__global__ void pack_wo_kernel(const float* __restrict__ wo, u16* __restrict__ wt) {
    int i = blockIdx.x * 256 + threadIdx.x;
    int n = i >> 9, k = i & 511;
    wt[(size_t)n * 512 + k] = f2bf(wo[(size_t)k * 512 + n]);
}

// ---------- 128x128 bf16 MFMA GEMM, A-only LDS dbuf, B direct from L2 -------
// R17: R16's B-direct experiment was voided by the register allocator — it
// targeted the 8-waves/SIMD tier (VGPR=64 < ~110 demand) because 32KB LDS
// made high occupancy look reachable, and spilled acc (WRITE 50->70MB).
// R0's identical-demand kernel got 88 regs cleanly only because 64KB LDS
// removed the occupancy incentive. Fix: amdgpu_waves_per_eu(2,4) — max=4
// pins the allocator to the 128-reg tier (no benefit squeezing lower),
// min=2 keeps the 256 cap. Everything else byte-identical to R16 (passed):
// B fragments per-lane from global/L2 (wqkvT 1.5MB / woT 0.5MB, L2-hot;
// per-wave read = 16 rows x 64B contiguous, coalesced), A in the verified
// gload_lds XOR-swizzle double-buffer, LDS 32KB -> 4 blocks/CU at <=128 VGPR.
// DMA bytes/iter halved (32->16KB) AND drain-domain concurrency doubled
// (2->4): the two levers the R10-R15 fit says multiply aggregate DMA service.
// B k-offset needs no XOR: fragment slot ((h*4+quad)^l7) reads stored chunk
// slot^(row&7) = h*4+quad -> global k-off = kt*64 + h*32 + quad*8.
template<int EPI, int NT>
__global__ __launch_bounds__(256) __attribute__((amdgpu_waves_per_eu(2, 4)))
void gemm128_kernel(const u16* __restrict__ A, const u16* __restrict__ Bt,
                    float* __restrict__ outf, const float* __restrict__ bo,
                    u16* __restrict__ Qb, u16* __restrict__ Kb, u16* __restrict__ Vb,
                    const float* __restrict__ bq, const float* __restrict__ bk,
                    const float* __restrict__ bv) {
    __shared__ __align__(16) u16 As[2][8192];   // 128 rows x 64 k, 16KB per buffer
    const int tid = threadIdx.x;
    const int bid = blockIdx.x;
    const int xcd = bid & 7;
    const int k8  = bid >> 3;                 // 0 .. 16*NT-1
    const int m0 = (xcd * 16 + k8 / NT) * 128;
    const int n0 = (k8 % NT) * 128;
    const int w = tid >> 6, lane = tid & 63;
    const int srow = w * 8 + (lane >> 3);               // + j*32
    const int sc   = (lane & 7) ^ ((lane >> 3) & 7);    // global 16B-chunk
    const u16* Ag = A + (size_t)(m0 + srow) * 512 + sc * 8;
    const int lofs = w * 512 + lane * 8;                // + j*2048 (u16 units)

    const int wrow = (w >> 1) * 64, wcol = (w & 1) * 64;
    const int lm = lane & 15, quad = lane >> 4;
    const int l7 = lm & 7;

    // B fragment base: row = n0 + wcol + ni*16 + lm, k-off = kt*64+h*32+quad*8
    const u16* Bg0 = Bt + (size_t)(n0 + wcol + lm) * 512 + quad * 8;

    f32x4 acc[4][4] = {};

#define STAGE_A(kt, b) do {                                      \
        const u16* Agp = Ag + (kt) * 64;                         \
        u16* Asp = As[(b)] + lofs;                               \
        gload_lds16(Agp,             Asp);                       \
        gload_lds16(Agp + 32 * 512,  Asp + 2048);                \
        gload_lds16(Agp + 64 * 512,  Asp + 4096);                \
        gload_lds16(Agp + 96 * 512,  Asp + 6144);                \
    } while (0)

    // prologue: stage tile 0 into buffer 0
    STAGE_A(0, 0);

    #pragma unroll 1
    for (int kt = 0; kt < 8; ++kt) {
        __syncthreads();   // tile kt DMA drained; other buffer's old reads done
        if (kt < 7) STAGE_A(kt + 1, (kt + 1) & 1);
        const u16* Ac = As[kt & 1];
        #pragma unroll
        for (int h = 0; h < 2; ++h) {
            const int slot = ((h * 4 + quad) ^ l7) * 8;
            short8 af[4], bf[4];
            #pragma unroll
            for (int mi = 0; mi < 4; ++mi)
                af[mi] = *(const short8*)(Ac + (wrow + mi * 16 + lm) * 64 + slot);
            #pragma unroll
            for (int ni = 0; ni < 4; ++ni)
                bf[ni] = *(const short8*)(Bg0 + (size_t)(ni * 16) * 512 + kt * 64 + h * 32);
            #pragma unroll
            for (int mi = 0; mi < 4; ++mi)
                #pragma unroll
                for (int ni = 0; ni < 4; ++ni)
                    acc[mi][ni] = __builtin_amdgcn_mfma_f32_16x16x32_bf16(af[mi], bf[ni], acc[mi][ni], 0, 0, 0);
        }
    }
#undef STAGE_A

    if (EPI == 1) {
        #pragma unroll
        for (int ni = 0; ni < 4; ++ni) {
            int ncol = n0 + wcol + ni * 16 + lm;
            float bias = bo[ncol];
            #pragma unroll
            for (int mi = 0; mi < 4; ++mi) {
                int mbase = m0 + wrow + mi * 16 + quad * 4;
                #pragma unroll
                for (int r = 0; r < 4; ++r)
                    outf[(size_t)(mbase + r) * 512 + ncol] = acc[mi][ni][r] + bias;
            }
        }
    } else {
        #pragma unroll
        for (int ni = 0; ni < 4; ++ni) {
            int ncol = n0 + wcol + ni * 16 + lm;
            int proj = ncol >> 9, hd = ncol & 511;
            int h = hd >> 6, d = hd & 63;
            const float* bptr = (proj == 0) ? bq : (proj == 1) ? bk : bv;
            u16* dst = (proj == 0) ? Qb : (proj == 1) ? Kb : Vb;
            float bias = bptr[hd];
            #pragma unroll
            for (int mi = 0; mi < 4; ++mi) {
                int mbase = m0 + wrow + mi * 16 + quad * 4;
                if (proj == 2) {
                    // Vt [head][d][t]: r -> t consecutive, same b. One ushort4.
                    int b = mbase >> 8, t = mbase & 255;
                    ushort4 v4;
                    v4.x = f2bf(acc[mi][ni][0] + bias);
                    v4.y = f2bf(acc[mi][ni][1] + bias);
                    v4.z = f2bf(acc[mi][ni][2] + bias);
                    v4.w = f2bf(acc[mi][ni][3] + bias);
                    *(ushort4*)(dst + ((size_t)((b * 8 + h) * 64 + d) * 256 + t)) = v4;
                } else {
                    #pragma unroll
                    for (int r = 0; r < 4; ++r) {
                        int mrow = mbase + r;
                        int b = mrow >> 8, t = mrow & 255;
                        dst[(size_t)((b * 8 + h) * 256 + t) * 64 + d] =
                            f2bf(acc[mi][ni][r] + bias);
                    }
                }
            }
        }
    }
}

// ---------------- MFMA flash attention (unchanged) ----------
// TWO wgs per (b,h) (iset 0: i in {0,3}; iset 1: i in {1,2}), XCD-co-located.
// K staged in LDS (XOR 16B-chunk swizzle, conflict-free); V fragments read
// directly from global Vt[head][d][t], hoisted above softmax. LDS 40KB/wg.
__global__ __launch_bounds__(256)
void attn_mfma_kernel(const u16* __restrict__ Qg, const u16* __restrict__ Kg,
                      const u16* __restrict__ Vtg, u16* __restrict__ attn) {
    __shared__ __align__(16) u16 lds[20480];   // K:0..16383 | P: 16384 + w*1024
    const int bid = blockIdx.x;
    const int head = (bid & 7) * 64 + ((bid >> 3) >> 1);
    const int iset = (bid >> 3) & 1;
    const int b = head >> 3, h = head & 7;
    const int tid = threadIdx.x;
    const size_t hb = (size_t)head * 16384;

    {
        const uint4* Ksrc = (const uint4*)(Kg + hb);
        uint4* L4 = (uint4*)lds;
        #pragma unroll
        for (int it = 0; it < 8; ++it) {
            int g = it * 256 + tid;
            int kr = g >> 3, kc = g & 7;
            L4[kr * 8 + (kc ^ (kr & 7))] = Ksrc[g];
        }
    }
    __syncthreads();

    const int w = tid >> 6, lane = tid & 63;
    const int lm = lane & 15, quad = lane >> 4;
    const int l7 = lm & 7;

    const int kx0 = (quad ^ l7) * 8;
    const int kx1 = ((4 + quad) ^ l7) * 8;
    const u16* Kbase = lds + lm * 64;
    const u16* Vg = Vtg + hb;
    const int Pbase = 16384 + w * 1024;
    const int x0 = (lm >> 3) & 1;
    const int pw_even = Pbase + quad * 16 + l7 + x0 * 8;
    const int pw_odd  = Pbase + quad * 16 + l7 + (x0 ^ 1) * 8;
    const int pr0 = Pbase + ((lm & 3) * 4 + (quad >> 1)) * 64
                  + (2 * (lm >> 2) + ((quad & 1) ^ (lm & 1))) * 8;

    #pragma unroll 1
    for (int ii = 0; ii < 2; ++ii) {
        const int i = iset ? (ii ? 2 : 1) : (ii ? 3 : 0);
        const int t0 = i * 64 + w * 16;
        short8 qa0 = *(const short8*)(Qg + hb + (size_t)(t0 + lm) * 64 + quad * 8);
        short8 qa1 = *(const short8*)(Qg + hb + (size_t)(t0 + lm) * 64 + 32 + quad * 8);
        f32x4 O[4] = {};
        float mr[4] = {-INFINITY, -INFINITY, -INFINITY, -INFINITY};
        float lr[4] = {0.f, 0.f, 0.f, 0.f};

        #pragma unroll 1
        for (int j = 0; j <= i; ++j) {
            f32x4 S[4] = {};
            #pragma unroll
            for (int ni = 0; ni < 4; ++ni) {
                const u16* kp = Kbase + j * 4096 + ni * 1024;
                short8 kb0 = *(const short8*)(kp + kx0);
                short8 kb1 = *(const short8*)(kp + kx1);
                S[ni] = __builtin_amdgcn_mfma_f32_16x16x32_bf16(qa0, kb0, S[ni], 0, 0, 0);
                S[ni] = __builtin_amdgcn_mfma_f32_16x16x32_bf16(qa1, kb1, S[ni], 0, 0, 0);
            }
            // hoisted V-fragment loads (P-independent; overlap softmax+barrier)
            short8 vb[4][2];
            #pragma unroll
            for (int nd = 0; nd < 4; ++nd) {
                const u16* vp = Vg + (size_t)(nd * 16 + lm) * 256 + j * 64;
                vb[nd][0] = *(const short8*)(vp + quad * 8);
                vb[nd][1] = *(const short8*)(vp + 32 + quad * 8);
            }
            if (j == i) {
                #pragma unroll
                for (int ni = 0; ni < 4; ++ni) {
                    int scol = ni * 16 + lm;
                    #pragma unroll
                    for (int rr = 0; rr < 4; ++rr) {
                        int tloc = w * 16 + quad * 4 + rr;
                        S[ni][rr] = (scol > tloc) ? -INFINITY : S[ni][rr] * 0.125f;
                    }
                }
            } else {
                #pragma unroll
                for (int ni = 0; ni < 4; ++ni)
                    #pragma unroll
                    for (int rr = 0; rr < 4; ++rr)
                        S[ni][rr] *= 0.125f;
            }
            float alpha[4];
            #pragma unroll
            for (int rr = 0; rr < 4; ++rr) {
                float mx = fmaxf(fmaxf(S[0][rr], S[1][rr]), fmaxf(S[2][rr], S[3][rr]));
                mx = fmaxf(mx, __shfl_xor(mx, 1));
                mx = fmaxf(mx, __shfl_xor(mx, 2));
                mx = fmaxf(mx, __shfl_xor(mx, 4));
                mx = fmaxf(mx, __shfl_xor(mx, 8));
                float mnew = fmaxf(mr[rr], mx);
                alpha[rr] = __expf(mr[rr] - mnew);
                mr[rr] = mnew;
            }
            float rs[4] = {0.f, 0.f, 0.f, 0.f};
            #pragma unroll
            for (int ni = 0; ni < 4; ++ni) {
                #pragma unroll
                for (int rr = 0; rr < 4; ++rr) {
                    float p = __expf(S[ni][rr] - mr[rr]);
                    rs[rr] += p;
                    int addr = ((rr & 1) ? pw_odd : pw_even) + (rr * 4 + ni) * 64;
                    lds[addr] = f2bf(p);
                }
            }
            #pragma unroll
            for (int rr = 0; rr < 4; ++rr) {
                float s = rs[rr];
                s += __shfl_xor(s, 1);
                s += __shfl_xor(s, 2);
                s += __shfl_xor(s, 4);
                s += __shfl_xor(s, 8);
                lr[rr] = lr[rr] * alpha[rr] + s;
                O[0][rr] *= alpha[rr]; O[1][rr] *= alpha[rr];
                O[2][rr] *= alpha[rr]; O[3][rr] *= alpha[rr];
            }
            __syncthreads();   // P write -> read ordering
            short8 pa0 = *(const short8*)(lds + pr0);
            short8 pa1 = *(const short8*)(lds + pr0 + 128);
            #pragma unroll
            for (int nd = 0; nd < 4; ++nd) {
                O[nd] = __builtin_amdgcn_mfma_f32_16x16x32_bf16(pa0, vb[nd][0], O[nd], 0, 0, 0);
                O[nd] = __builtin_amdgcn_mfma_f32_16x16x32_bf16(pa1, vb[nd][1], O[nd], 0, 0, 0);
            }
        }
        #pragma unroll
        for (int rr = 0; rr < 4; ++rr) {
            float inv = 1.0f / lr[rr];
            int t = t0 + quad * 4 + rr;
            u16* op = attn + (size_t)(b * 256 + t) * 512 + h * 64 + lm;
            op[0]  = f2bf(O[0][rr] * inv);
            op[16] = f2bf(O[1][rr] * inv);
            op[32] = f2bf(O[2][rr] * inv);
            op[48] = f2bf(O[3][rr] * inv);
        }
    }
}

extern "C" void kernel_launch(void* const* d_in, const int* in_sizes, int n_in,
                              void* d_out, int out_size, void* d_ws, size_t ws_size,
                              hipStream_t stream) {
    const float* x  = (const float*)d_in[0];
    const float* wq = (const float*)d_in[1];
    const float* wk = (const float*)d_in[2];
    const float* wv = (const float*)d_in[3];
    const float* bq = (const float*)d_in[4];
    const float* bk = (const float*)d_in[5];
    const float* bv = (const float*)d_in[6];
    const float* wo = (const float*)d_in[7];
    const float* bo = (const float*)d_in[8];
    float* out = (float*)d_out;

    char* ws = (char*)d_ws;
    const size_t SZ = 16777216;                  // 16384*512*2 bytes
    u16* xb    = (u16*)(ws);
    u16* Qb    = (u16*)(ws + SZ);
    u16* Kb    = (u16*)(ws + 2 * SZ);
    u16* Vt    = (u16*)(ws + 3 * SZ);            // [head][d][t]
    u16* attn  = (u16*)(ws + 4 * SZ);
    u16* wqkvT = (u16*)(ws + 5 * SZ);
    u16* woT   = (u16*)(ws + 5 * SZ + 1572864);

    cast_x_kernel<<<8192, 256, 0, stream>>>(x, xb);
    pack_wqkv_kernel<<<3072, 256, 0, stream>>>(wq, wk, wv, wqkvT);
    pack_wo_kernel<<<1024, 256, 0, stream>>>(wo, woT);

    gemm128_kernel<0, 12><<<1536, 256, 0, stream>>>(
        xb, wqkvT, nullptr, nullptr, Qb, Kb, Vt, bq, bk, bv);

    attn_mfma_kernel<<<1024, 256, 0, stream>>>(Qb, Kb, Vt, attn);

    gemm128_kernel<1, 4><<<512, 256, 0, stream>>>(
        attn, woT, out, bo, nullptr, nullptr, nullptr, nullptr, nullptr, nullptr);
}

// Round 8
// 182.980 us; speedup vs baseline: 1.2202x; 1.2041x over previous
//
#include <hip/hip_runtime.h>

typedef unsigned int   u32;
typedef unsigned short u16;
typedef __attribute__((ext_vector_type(8))) short short8;
typedef __attribute__((ext_vector_type(4))) float f32x4;

// B=64 T=256 C=512 H=8 D=64; M = B*T = 16384; K = 512; Nqkv = 1536

__device__ __forceinline__ u16 f2bf(float f) {
    u32 u = __float_as_uint(f);
    u += 0x7fffu + ((u >> 16) & 1u);   // RNE
    return (u16)(u >> 16);
}

// async global->LDS 16B DMA; LDS dest must be wave-uniform base + lane*16.
__device__ __forceinline__ void gload_lds16(const u16* g, u16* l) {
    __builtin_amdgcn_global_load_lds(
        (const __attribute__((address_space(1))) u32*)(const void*)g,
        (__attribute__((address_space(3))) u32*)(void*)l, 16, 0, 0);
}

// ---------------- cast x (fp32 -> bf16) ----------------
__global__ void cast_x_kernel(const float* __restrict__ x, u16* __restrict__ xb) {
    int i = blockIdx.x * 256 + threadIdx.x;
    float4 v = ((const float4*)x)[i];
    ushort4 o;
    o.x = f2bf(v.x); o.y = f2bf(v.y); o.z = f2bf(v.z); o.w = f2bf(v.w);
    ((ushort4*)xb)[i] = o;
}

// -------- pack wq|wk|wv -> bf16 [1536][512] transposed --------
__global__ void pack_wqkv_kernel(const float* __restrict__ wq, const float* __restrict__ wk,
                                 const float* __restrict__ wv, u16* __restrict__ wt) {
    int i = blockIdx.x * 256 + threadIdx.x;
    int n = i >> 9, c = i & 511;
    int proj = n >> 9, hd = n & 511;
    int h = hd >> 6, d = hd & 63;
    const float* w = (proj == 0) ? wq : (proj == 1) ? wk : wv;
    wt[(size_t)n * 512 + c] = f2bf(w[h * 32768 + c * 64 + d]);
}

// -------- pack wo [512][512] -> bf16 transposed [n][k] --------
__global__ void pack_wo_kernel(const float* __restrict__ wo, u16* __restrict__ wt) {
    int i = blockIdx.x * 256 + threadIdx.x;
    int n = i >> 9, k = i & 511;
    wt[(size_t)n * 512 + k] = f2bf(wo[(size_t)k * 512 + n]);
}

// ---------------- 128x128 bf16 MFMA GEMM, K=512, TN, BK=64 ----------------
// R18: restored R12-exact config (best measured: QKV 62us, VGPR 52, no spill).
// R13-R17 post-mortems: B-direct / fat-tile variants all voided by the
// register allocator (spill signatures: VGPR 36/104/64 vs demand, WRITE +20-
// 33MB scratch); occupancy attributes did not move the allocator. The 8-wave
// 2-buffer A+B staged structure is the known-clean point. Only delta vs R12:
// proj==2 (V) epilogue uses one ushort4 store per acc row-quad (t-consecutive,
// proven in R16/R17 which passed).
// Staging map (verified): row r = j*64 + w*8 + (l>>3), chunk slot=l&7,
// global chunk c=slot^(r&7); LDS dest = buf + j*4096 + tid*8. Fragment reads
// slot ((h*4+quad)^(lm&7)) -> conflict-free reads AND writes.
template<int EPI, int NT>
__global__ __launch_bounds__(512)
void gemm128_kernel(const u16* __restrict__ A, const u16* __restrict__ Bt,
                    float* __restrict__ outf, const float* __restrict__ bo,
                    u16* __restrict__ Qb, u16* __restrict__ Kb, u16* __restrict__ Vb,
                    const float* __restrict__ bq, const float* __restrict__ bk,
                    const float* __restrict__ bv) {
    __shared__ __align__(16) u16 As[2][8192];   // 2 x (128 rows x 64 k) = 32KB
    __shared__ __align__(16) u16 Bs[2][8192];
    const int tid = threadIdx.x;
    const int bid = blockIdx.x;
    const int xcd = bid & 7;
    const int k8  = bid >> 3;
    const int m0 = (xcd * 16 + k8 / NT) * 128;
    const int n0 = (k8 % NT) * 128;
    const int w = tid >> 6, lane = tid & 63;
    const int srow = w * 8 + (lane >> 3);               // + j*64 per call
    const int sc   = (lane & 7) ^ ((lane >> 3) & 7);    // global 16B-chunk
    const u16* Ag = A  + (size_t)(m0 + srow) * 512 + sc * 8;
    const u16* Bg = Bt + (size_t)(n0 + srow) * 512 + sc * 8;
    const int lofs = tid * 8;                           // + j*4096 (u16 units)

    const int wrow = (w >> 2) * 64, wcol = (w & 3) * 32;
    const int lm = lane & 15, quad = lane >> 4;
    const int l7 = lm & 7;

    f32x4 acc[4][2] = {};

    // stage tile kt into buffer b: 4 DMA loads/thread (2 for A, 2 for B)
#define STAGE(kt, b) do {                                        \
        const u16* Agp = Ag + (kt) * 64;                         \
        const u16* Bgp = Bg + (kt) * 64;                         \
        u16* Asp = As[(b)] + lofs;                               \
        u16* Bsp = Bs[(b)] + lofs;                               \
        gload_lds16(Agp,            Asp);                        \
        gload_lds16(Agp + 64 * 512, Asp + 4096);                 \
        gload_lds16(Bgp,            Bsp);                        \
        gload_lds16(Bgp + 64 * 512, Bsp + 4096);                 \
    } while (0)

    // prologue: stage tile 0 into buffer 0
    STAGE(0, 0);

    #pragma unroll 1
    for (int kt = 0; kt < 8; ++kt) {
        __syncthreads();   // tile kt DMA drained; other buffer's old reads done
        if (kt < 7) STAGE(kt + 1, (kt + 1) & 1);
        const u16* Ac = As[kt & 1];
        const u16* Bc = Bs[kt & 1];
        short8 af[2][4], bf[2][2];
        #pragma unroll
        for (int h = 0; h < 2; ++h) {
            const int slot = ((h * 4 + quad) ^ l7) * 8;
            #pragma unroll
            for (int mi = 0; mi < 4; ++mi)
                af[h][mi] = *(const short8*)(Ac + (wrow + mi * 16 + lm) * 64 + slot);
            #pragma unroll
            for (int ni = 0; ni < 2; ++ni)
                bf[h][ni] = *(const short8*)(Bc + (wcol + ni * 16 + lm) * 64 + slot);
        }
        #pragma unroll
        for (int h = 0; h < 2; ++h)
            #pragma unroll
            for (int mi = 0; mi < 4; ++mi)
                #pragma unroll
                for (int ni = 0; ni < 2; ++ni)
                    acc[mi][ni] = __builtin_amdgcn_mfma_f32_16x16x32_bf16(af[h][mi], bf[h][ni], acc[mi][ni], 0, 0, 0);
    }
#undef STAGE

    if (EPI == 1) {
        #pragma unroll
        for (int ni = 0; ni < 2; ++ni) {
            int ncol = n0 + wcol + ni * 16 + lm;
            float bias = bo[ncol];
            #pragma unroll
            for (int mi = 0; mi < 4; ++mi) {
                int mbase = m0 + wrow + mi * 16 + quad * 4;
                #pragma unroll
                for (int r = 0; r < 4; ++r)
                    outf[(size_t)(mbase + r) * 512 + ncol] = acc[mi][ni][r] + bias;
            }
        }
    } else {
        #pragma unroll
        for (int ni = 0; ni < 2; ++ni) {
            int ncol = n0 + wcol + ni * 16 + lm;
            int proj = ncol >> 9, hd = ncol & 511;
            int h = hd >> 6, d = hd & 63;
            const float* bptr = (proj == 0) ? bq : (proj == 1) ? bk : bv;
            u16* dst = (proj == 0) ? Qb : (proj == 1) ? Kb : Vb;
            float bias = bptr[hd];
            #pragma unroll
            for (int mi = 0; mi < 4; ++mi) {
                int mbase = m0 + wrow + mi * 16 + quad * 4;
                if (proj == 2) {
                    // Vt [head][d][t]: r -> t consecutive, same b. One ushort4.
                    int b = mbase >> 8, t = mbase & 255;
                    ushort4 v4;
                    v4.x = f2bf(acc[mi][ni][0] + bias);
                    v4.y = f2bf(acc[mi][ni][1] + bias);
                    v4.z = f2bf(acc[mi][ni][2] + bias);
                    v4.w = f2bf(acc[mi][ni][3] + bias);
                    *(ushort4*)(dst + ((size_t)((b * 8 + h) * 64 + d) * 256 + t)) = v4;
                } else {
                    #pragma unroll
                    for (int r = 0; r < 4; ++r) {
                        int mrow = mbase + r;
                        int b = mrow >> 8, t = mrow & 255;
                        dst[(size_t)((b * 8 + h) * 256 + t) * 64 + d] =
                            f2bf(acc[mi][ni][r] + bias);
                    }
                }
            }
        }
    }
}

// ---------------- MFMA flash attention ----------
// R18 change: the per-j-iter __syncthreads REMOVED. P is wave-private
// (Pbase = 16384 + w*1024: written and read only by wave w), and LDS
// instructions from one wavefront execute in order, so write->read ordering
// within the wave needs no barrier. The barrier was lock-stepping the 4
// waves 5x per wg: every wave waited for the slowest softmax chain before
// any PV MFMA could issue. Without it each wave is an independent pipeline
// (softmax VALU of one wave overlaps PV MFMA of another on the same SIMD,
// m114). sched_barrier(0) between P-store and P-read pins compile-time
// order for the may-alias DS ops. K-staging barrier (cross-wave) kept.
__global__ __launch_bounds__(256)
void attn_mfma_kernel(const u16* __restrict__ Qg, const u16* __restrict__ Kg,
                      const u16* __restrict__ Vtg, u16* __restrict__ attn) {
    __shared__ __align__(16) u16 lds[20480];   // K:0..16383 | P: 16384 + w*1024
    const int bid = blockIdx.x;
    const int head = (bid & 7) * 64 + ((bid >> 3) >> 1);
    const int iset = (bid >> 3) & 1;
    const int b = head >> 3, h = head & 7;
    const int tid = threadIdx.x;
    const size_t hb = (size_t)head * 16384;

    {
        const uint4* Ksrc = (const uint4*)(Kg + hb);
        uint4* L4 = (uint4*)lds;
        #pragma unroll
        for (int it = 0; it < 8; ++it) {
            int g = it * 256 + tid;
            int kr = g >> 3, kc = g & 7;
            L4[kr * 8 + (kc ^ (kr & 7))] = Ksrc[g];
        }
    }
    __syncthreads();

    const int w = tid >> 6, lane = tid & 63;
    const int lm = lane & 15, quad = lane >> 4;
    const int l7 = lm & 7;

    const int kx0 = (quad ^ l7) * 8;
    const int kx1 = ((4 + quad) ^ l7) * 8;
    const u16* Kbase = lds + lm * 64;
    const u16* Vg = Vtg + hb;
    const int Pbase = 16384 + w * 1024;
    const int x0 = (lm >> 3) & 1;
    const int pw_even = Pbase + quad * 16 + l7 + x0 * 8;
    const int pw_odd  = Pbase + quad * 16 + l7 + (x0 ^ 1) * 8;
    const int pr0 = Pbase + ((lm & 3) * 4 + (quad >> 1)) * 64
                  + (2 * (lm >> 2) + ((quad & 1) ^ (lm & 1))) * 8;

    #pragma unroll 1
    for (int ii = 0; ii < 2; ++ii) {
        const int i = iset ? (ii ? 2 : 1) : (ii ? 3 : 0);
        const int t0 = i * 64 + w * 16;
        short8 qa0 = *(const short8*)(Qg + hb + (size_t)(t0 + lm) * 64 + quad * 8);
        short8 qa1 = *(const short8*)(Qg + hb + (size_t)(t0 + lm) * 64 + 32 + quad * 8);
        f32x4 O[4] = {};
        float mr[4] = {-INFINITY, -INFINITY, -INFINITY, -INFINITY};
        float lr[4] = {0.f, 0.f, 0.f, 0.f};

        #pragma unroll 1
        for (int j = 0; j <= i; ++j) {
            f32x4 S[4] = {};
            #pragma unroll
            for (int ni = 0; ni < 4; ++ni) {
                const u16* kp = Kbase + j * 4096 + ni * 1024;
                short8 kb0 = *(const short8*)(kp + kx0);
                short8 kb1 = *(const short8*)(kp + kx1);
                S[ni] = __builtin_amdgcn_mfma_f32_16x16x32_bf16(qa0, kb0, S[ni], 0, 0, 0);
                S[ni] = __builtin_amdgcn_mfma_f32_16x16x32_bf16(qa1, kb1, S[ni], 0, 0, 0);
            }
            // hoisted V-fragment loads (P-independent; overlap softmax)
            short8 vb[4][2];
            #pragma unroll
            for (int nd = 0; nd < 4; ++nd) {
                const u16* vp = Vg + (size_t)(nd * 16 + lm) * 256 + j * 64;
                vb[nd][0] = *(const short8*)(vp + quad * 8);
                vb[nd][1] = *(const short8*)(vp + 32 + quad * 8);
            }
            if (j == i) {
                #pragma unroll
                for (int ni = 0; ni < 4; ++ni) {
                    int scol = ni * 16 + lm;
                    #pragma unroll
                    for (int rr = 0; rr < 4; ++rr) {
                        int tloc = w * 16 + quad * 4 + rr;
                        S[ni][rr] = (scol > tloc) ? -INFINITY : S[ni][rr] * 0.125f;
                    }
                }
            } else {
                #pragma unroll
                for (int ni = 0; ni < 4; ++ni)
                    #pragma unroll
                    for (int rr = 0; rr < 4; ++rr)
                        S[ni][rr] *= 0.125f;
            }
            float alpha[4];
            #pragma unroll
            for (int rr = 0; rr < 4; ++rr) {
                float mx = fmaxf(fmaxf(S[0][rr], S[1][rr]), fmaxf(S[2][rr], S[3][rr]));
                mx = fmaxf(mx, __shfl_xor(mx, 1));
                mx = fmaxf(mx, __shfl_xor(mx, 2));
                mx = fmaxf(mx, __shfl_xor(mx, 4));
                mx = fmaxf(mx, __shfl_xor(mx, 8));
                float mnew = fmaxf(mr[rr], mx);
                alpha[rr] = __expf(mr[rr] - mnew);
                mr[rr] = mnew;
            }
            float rs[4] = {0.f, 0.f, 0.f, 0.f};
            #pragma unroll
            for (int ni = 0; ni < 4; ++ni) {
                #pragma unroll
                for (int rr = 0; rr < 4; ++rr) {
                    float p = __expf(S[ni][rr] - mr[rr]);
                    rs[rr] += p;
                    int addr = ((rr & 1) ? pw_odd : pw_even) + (rr * 4 + ni) * 64;
                    lds[addr] = f2bf(p);
                }
            }
            #pragma unroll
            for (int rr = 0; rr < 4; ++rr) {
                float s = rs[rr];
                s += __shfl_xor(s, 1);
                s += __shfl_xor(s, 2);
                s += __shfl_xor(s, 4);
                s += __shfl_xor(s, 8);
                lr[rr] = lr[rr] * alpha[rr] + s;
                O[0][rr] *= alpha[rr]; O[1][rr] *= alpha[rr];
                O[2][rr] *= alpha[rr]; O[3][rr] *= alpha[rr];
            }
            // NO __syncthreads: P is wave-private; same-wave DS ops are
            // in-order. sched_barrier pins compile-time store->load order.
            __builtin_amdgcn_sched_barrier(0);
            short8 pa0 = *(const short8*)(lds + pr0);
            short8 pa1 = *(const short8*)(lds + pr0 + 128);
            #pragma unroll
            for (int nd = 0; nd < 4; ++nd) {
                O[nd] = __builtin_amdgcn_mfma_f32_16x16x32_bf16(pa0, vb[nd][0], O[nd], 0, 0, 0);
                O[nd] = __builtin_amdgcn_mfma_f32_16x16x32_bf16(pa1, vb[nd][1], O[nd], 0, 0, 0);
            }
        }
        #pragma unroll
        for (int rr = 0; rr < 4; ++rr) {
            float inv = 1.0f / lr[rr];
            int t = t0 + quad * 4 + rr;
            u16* op = attn + (size_t)(b * 256 + t) * 512 + h * 64 + lm;
            op[0]  = f2bf(O[0][rr] * inv);
            op[16] = f2bf(O[1][rr] * inv);
            op[32] = f2bf(O[2][rr] * inv);
            op[48] = f2bf(O[3][rr] * inv);
        }
    }
}

extern "C" void kernel_launch(void* const* d_in, const int* in_sizes, int n_in,
                              void* d_out, int out_size, void* d_ws, size_t ws_size,
                              hipStream_t stream) {
    const float* x  = (const float*)d_in[0];
    const float* wq = (const float*)d_in[1];
    const float* wk = (const float*)d_in[2];
    const float* wv = (const float*)d_in[3];
    const float* bq = (const float*)d_in[4];
    const float* bk = (const float*)d_in[5];
    const float* bv = (const float*)d_in[6];
    const float* wo = (const float*)d_in[7];
    const float* bo = (const float*)d_in[8];
    float* out = (float*)d_out;

    char* ws = (char*)d_ws;
    const size_t SZ = 16777216;                  // 16384*512*2 bytes
    u16* xb    = (u16*)(ws);
    u16* Qb    = (u16*)(ws + SZ);
    u16* Kb    = (u16*)(ws + 2 * SZ);
    u16* Vt    = (u16*)(ws + 3 * SZ);            // [head][d][t]
    u16* attn  = (u16*)(ws + 4 * SZ);
    u16* wqkvT = (u16*)(ws + 5 * SZ);
    u16* woT   = (u16*)(ws + 5 * SZ + 1572864);

    cast_x_kernel<<<8192, 256, 0, stream>>>(x, xb);
    pack_wqkv_kernel<<<3072, 256, 0, stream>>>(wq, wk, wv, wqkvT);
    pack_wo_kernel<<<1024, 256, 0, stream>>>(wo, woT);

    gemm128_kernel<0, 12><<<1536, 512, 0, stream>>>(
        xb, wqkvT, nullptr, nullptr, Qb, Kb, Vt, bq, bk, bv);

    attn_mfma_kernel<<<1024, 256, 0, stream>>>(Qb, Kb, Vt, attn);

    gemm128_kernel<1, 4><<<512, 512, 0, stream>>>(
        attn, woT, out, bo, nullptr, nullptr, nullptr, nullptr, nullptr, nullptr);
}